// Round 4
// baseline (264.428 us; speedup 1.0000x reference)
//
#include <hip/hip_runtime.h>

typedef float f32x4 __attribute__((ext_vector_type(4)));

// Problem shape (fixed by setup_inputs): B=64, C=1024, H*W=1024, M=768.
#define NB 64
#define NC 1024
#define HW 1024
#define HW4 256            // HW / 4
#define NCHUNK 4           // batch chunks; 16 batches = 64 MB of fm per chunk
#define BPC (NB / NCHUNK)  // 16 batches per chunk
#define CCH 32             // channel splits in the GEMV
#define CPC (NC / CCH)     // 32 channels per split

// Kernel A (per chunk): partial[cchunk][bb][hw] = sum over CPC channels of
// fm[b0+bb, c, hw] * w[c]. Coalesced 16 B/lane reads; fills L3 with this
// chunk's fm (64 MB) for the apply kernel two launches later.
__global__ void adl_gemv_chunk(const float* __restrict__ fm_chunk,
                               const float* __restrict__ w,
                               float* __restrict__ partial) {
    const int cchunk = blockIdx.x;           // 0..CCH-1
    const int bb     = blockIdx.y;           // 0..BPC-1
    const int t      = threadIdx.x;          // 0..255 -> hw 4t..4t+3
    const f32x4* fm4 = (const f32x4*)fm_chunk;
    f32x4 acc = {0.f, 0.f, 0.f, 0.f};
    const int cbase = cchunk * CPC;
    #pragma unroll 8
    for (int ci = 0; ci < CPC; ++ci) {
        const int c = cbase + ci;
        const f32x4 v = fm4[((size_t)(bb * NC + c)) * HW4 + t];
        acc += v * w[c];
    }
    ((f32x4*)partial)[((size_t)(cchunk * BPC + bb)) * HW4 + t] = acc;
}

// Kernel B (per chunk): reduce partials -> logit, sigmoid -> attn output,
// exact top-M drop mask via per-element descending rank with index tie-break
// (matches lax.top_k). Rank on the LOGIT (sigmoid strictly monotone).
__global__ void adl_topk_chunk(const float* __restrict__ partial,
                               const float* __restrict__ conv_b,
                               const int* __restrict__ Mptr,
                               int b0,
                               float* __restrict__ attn_out,
                               float* __restrict__ mask) {
    __shared__ f32x4 s_sh4[HW4];
    float* s_sh = (float*)s_sh4;
    const int slice = blockIdx.x;            // 0..3
    const int bb    = blockIdx.y;            // 0..BPC-1
    const int tid   = threadIdx.x;           // 0..255
    const float bias = conv_b[0];
    #pragma unroll
    for (int q = 0; q < 4; ++q) {
        const int t = q * 256 + tid;
        float s = bias;
        #pragma unroll 8
        for (int k = 0; k < CCH; ++k)
            s += partial[((size_t)(k * BPC + bb)) * HW + t];
        s_sh[t] = s;
    }
    __syncthreads();
    const int t = slice * 256 + tid;         // this thread's element
    const float sv = s_sh[t];
    const int M = *Mptr;
    int r = 0;
    #pragma unroll 4
    for (int j4 = 0; j4 < HW4; ++j4) {
        const f32x4 v = s_sh4[j4];           // broadcast LDS read
        const int j = j4 * 4;
        r += (v.x > sv) || (v.x == sv && (j + 0) < t);
        r += (v.y > sv) || (v.y == sv && (j + 1) < t);
        r += (v.z > sv) || (v.z == sv && (j + 2) < t);
        r += (v.w > sv) || (v.w == sv && (j + 3) < t);
    }
    attn_out[(size_t)(b0 + bb) * HW + t] = 1.0f / (1.0f + expf(-sv));
    mask[(size_t)bb * HW + t] = (r < M) ? 0.0f : 1.0f;
}

// Kernel C (per chunk): out = fm * mask for this chunk's 16 batches. The fm
// chunk (64 MB) is L3-resident from kernel A; nontemporal stores keep the
// out-stream from evicting it. Forward order (round-2 reverse regressed).
__global__ void adl_apply_chunk(const float* __restrict__ fm_chunk,
                                const float* __restrict__ mask,
                                float* __restrict__ out_chunk) {
    const f32x4* fm4   = (const f32x4*)fm_chunk;
    const f32x4* mask4 = (const f32x4*)mask;
    f32x4* out4        = (f32x4*)out_chunk;
    const size_t total4 = (size_t)BPC * NC * HW4;   // 4,194,304
    const size_t stride = (size_t)gridDim.x * blockDim.x;
    for (size_t i = (size_t)blockIdx.x * blockDim.x + threadIdx.x;
         i < total4; i += stride) {
        const int hw4 = (int)(i & (HW4 - 1));
        const int bb  = (int)(i >> 18);             // i / (NC*HW4)
        const f32x4 m = mask4[bb * HW4 + hw4];
        const f32x4 v = fm4[i];
        __builtin_nontemporal_store(v * m, &out4[i]);
    }
}

extern "C" void kernel_launch(void* const* d_in, const int* in_sizes, int n_in,
                              void* d_out, int out_size, void* d_ws, size_t ws_size,
                              hipStream_t stream) {
    const float* fm   = (const float*)d_in[0];   // [64,1024,32,32] f32
    const float* w    = (const float*)d_in[1];   // [1024] f32
    const float* bias = (const float*)d_in[2];   // [1] f32
    const int*   Mptr = (const int*)d_in[3];     // scalar int (768)

    float* out      = (float*)d_out;                       // dropped [B,C,H,W]
    float* attn_out = out + (size_t)NB * NC * HW;          // attn [B,1,H,W]

    // Per-chunk scratch, reused across chunks (stream-serial, deterministic):
    // partial [CCH][BPC][HW] f32 = 2 MB, mask [BPC][HW] f32 = 64 KB.
    float* partial = (float*)d_ws;
    float* mask    = partial + (size_t)CCH * BPC * HW;

    const size_t chunk_elems = (size_t)BPC * NC * HW;
    for (int k = 0; k < NCHUNK; ++k) {
        const float* fm_chunk  = fm  + (size_t)k * chunk_elems;
        float*       out_chunk = out + (size_t)k * chunk_elems;
        adl_gemv_chunk<<<dim3(CCH, BPC), 256, 0, stream>>>(fm_chunk, w, partial);
        adl_topk_chunk<<<dim3(4, BPC), 256, 0, stream>>>(partial, bias, Mptr,
                                                         k * BPC, attn_out, mask);
        adl_apply_chunk<<<2048, 256, 0, stream>>>(fm_chunk, mask, out_chunk);
    }
}

// Round 5
// 161.279 us; speedup vs baseline: 1.6396x; 1.6396x over previous
//
#include <hip/hip_runtime.h>

typedef float f32x4 __attribute__((ext_vector_type(4)));

// Problem shape (fixed by setup_inputs): B=64, C=1024, H*W=1024, M=768.
#define NB 64
#define NC 1024
#define HW 1024
#define HW4 256          // HW / 4
#define CCH 16           // channel splits in the GEMV
#define CPC (NC / CCH)   // 64 channels per split
#define CGRP 16          // channel groups in apply
#define CPG (NC / CGRP)  // 64 channels per group

// Kernel A: split-K GEMV, stream-structured. Block (cg, b); thread t owns
// hw4 = t for the whole block, so the inner loop over CPC channels is just
// base += HW4 (4 KB row stride), load f32x4, fma. Fully coalesced.
__global__ void __launch_bounds__(256)
adl_gemv(const float* __restrict__ fm,
         const float* __restrict__ w,
         float* __restrict__ partial) {
    const int cg = blockIdx.x;               // 0..CCH-1
    const int b  = blockIdx.y;               // 0..NB-1
    const int t  = threadIdx.x;              // 0..255 == hw4
    const f32x4* fm4 = (const f32x4*)fm;
    const int cbase = cg * CPC;
    size_t base = ((size_t)(b * NC + cbase)) * HW4 + t;
    f32x4 acc = {0.f, 0.f, 0.f, 0.f};
    #pragma unroll 8
    for (int ci = 0; ci < CPC; ++ci) {
        acc += fm4[base] * w[cbase + ci];    // w: wave-uniform s_load
        base += HW4;
    }
    ((f32x4*)partial)[((size_t)(cg * NB + b)) * HW4 + t] = acc;
}

// Kernel B: reduce partials -> logit, sigmoid -> attn output, exact top-M
// drop mask via per-element descending rank with index tie-break (matches
// lax.top_k). Rank on the LOGIT (sigmoid strictly monotone). Grid (4, NB).
__global__ void __launch_bounds__(256)
adl_topk_mask(const float* __restrict__ partial,
              const float* __restrict__ conv_b,
              const int* __restrict__ Mptr,
              float* __restrict__ attn_out,
              float* __restrict__ mask) {
    __shared__ f32x4 s_sh4[HW4];
    float* s_sh = (float*)s_sh4;
    const int slice = blockIdx.x;            // 0..3
    const int b     = blockIdx.y;            // 0..NB-1
    const int tid   = threadIdx.x;           // 0..255
    const float bias = conv_b[0];
    #pragma unroll
    for (int q = 0; q < 4; ++q) {
        const int t = q * 256 + tid;
        float s = bias;
        #pragma unroll 8
        for (int k = 0; k < CCH; ++k)
            s += partial[((size_t)(k * NB + b)) * HW + t];
        s_sh[t] = s;
    }
    __syncthreads();
    const int t = slice * 256 + tid;         // this thread's element
    const float sv = s_sh[t];
    const int M = *Mptr;
    int r = 0;
    #pragma unroll 4
    for (int j4 = 0; j4 < HW4; ++j4) {
        const f32x4 v = s_sh4[j4];           // broadcast LDS read
        const int j = j4 * 4;
        r += (v.x > sv) || (v.x == sv && (j + 0) < t);
        r += (v.y > sv) || (v.y == sv && (j + 1) < t);
        r += (v.z > sv) || (v.z == sv && (j + 2) < t);
        r += (v.w > sv) || (v.w == sv && (j + 3) < t);
    }
    attn_out[(size_t)b * HW + t] = 1.0f / (1.0f + expf(-sv));
    mask[(size_t)b * HW + t] = (r < M) ? 0.0f : 1.0f;
}

// Kernel C: out = fm * mask, stream-structured. Block (cg, b); thread t owns
// hw4 = t, so the mask element is LOOP-INVARIANT (one 16 B load per thread),
// and the inner loop over CPG channels is load / mul / nt-store / base+=HW4.
// NT loads: fm is dead after this kernel (hits still hit, no re-allocation).
// NT stores: out-stream never pollutes caches.
__global__ void __launch_bounds__(256)
adl_apply(const float* __restrict__ fm,
          const float* __restrict__ mask,
          float* __restrict__ out) {
    const int cg = blockIdx.x;               // 0..CGRP-1
    const int b  = blockIdx.y;               // 0..NB-1
    const int t  = threadIdx.x;              // 0..255 == hw4
    const f32x4* fm4   = (const f32x4*)fm;
    const f32x4* mask4 = (const f32x4*)mask;
    f32x4* out4        = (f32x4*)out;
    const f32x4 m = mask4[b * HW4 + t];
    size_t base = ((size_t)(b * NC + cg * CPG)) * HW4 + t;
    #pragma unroll 4
    for (int ci = 0; ci < CPG; ++ci) {
        const f32x4 v = __builtin_nontemporal_load(&fm4[base]);
        __builtin_nontemporal_store(v * m, &out4[base]);
        base += HW4;
    }
}

extern "C" void kernel_launch(void* const* d_in, const int* in_sizes, int n_in,
                              void* d_out, int out_size, void* d_ws, size_t ws_size,
                              hipStream_t stream) {
    const float* fm   = (const float*)d_in[0];   // [64,1024,32,32] f32
    const float* w    = (const float*)d_in[1];   // [1024] f32
    const float* bias = (const float*)d_in[2];   // [1] f32
    const int*   Mptr = (const int*)d_in[3];     // scalar int (768)

    float* out      = (float*)d_out;                       // dropped [B,C,H,W]
    float* attn_out = out + (size_t)NB * NC * HW;          // attn [B,1,H,W]

    // Workspace: partial [CCH][NB][HW] f32 (4 MB) + mask [NB][HW] f32 (256 KB).
    float* partial = (float*)d_ws;
    float* mask    = partial + (size_t)CCH * NB * HW;

    adl_gemv<<<dim3(CCH, NB), 256, 0, stream>>>(fm, w, partial);
    adl_topk_mask<<<dim3(4, NB), 256, 0, stream>>>(partial, bias, Mptr, attn_out, mask);
    adl_apply<<<dim3(CGRP, NB), 256, 0, stream>>>(fm, mask, out);
}